// Round 8
// baseline (98.419 us; speedup 1.0000x reference)
//
#include <hip/hip_runtime.h>
#include <stddef.h>

namespace {
constexpr int Hc = 256, Wc = 256, Cc = 64, Bc = 4, Dc = 81;
constexpr int CH = Hc * Wc;   // channel stride in floats
constexpr int ROWF = 264;     // padded ring row: 4 pad + 256 + 4 pad
}

// async global->LDS DMA: per-lane global src, wave-uniform LDS dest + lane*16
#define GLOAD_LDS16(g, l)                                                   \
    __builtin_amdgcn_global_load_lds(                                       \
        (const __attribute__((address_space(1))) void*)(g),                 \
        (__attribute__((address_space(3))) void*)(l), 16, 0, 0)

#define PIN() asm volatile("" ::: "memory")

// ring row base for (wave wi, slot S)
#define xrow(S) (smem + (((wi) * 4 + (S)) * ROWF))

// 36 FMAs: pixel w=4t+s, offset j=jj-4 -> padded window idx s-jj+8
#define FMAS(P, A, Bv, Cv)                                                  \
    do {                                                                    \
        const float w_[12] = {A.x,  A.y,  A.z,  A.w,  Bv.x, Bv.y,           \
                              Bv.z, Bv.w, Cv.x, Cv.y, Cv.z, Cv.w};          \
        const float pv_[4] = {P.x, P.y, P.z, P.w};                          \
        _Pragma("unroll") for (int jj = 0; jj < 9; ++jj)                    \
            _Pragma("unroll") for (int s = 0; s < 4; ++s)                   \
                acc[jj][s] += pv_[s] * w_[s - jj + 8];                      \
    } while (0)

// issue the 3-quad window read of ring slot S into register set X
#define RDWIN(S, X)                                                         \
    do {                                                                    \
        const float* rp_ = xrow(S) + 4 * t;                                 \
        w0##X = *(const float4*)(rp_);                                      \
        w1##X = *(const float4*)(rp_ + 4);                                  \
        w2##X = *(const float4*)(rp_ + 8);                                  \
    } while (0)

// Steady-state step c (slot Q=c&3): counted waits, never drain to 0.
//  vmcnt(3): queue [DMA(c+1), x1(c), DMA(c+2), x1(c+1), DMA(c+3)] ->
//            completes DMA(c+1) (slot QN readable) and x1(c) (FMA operand).
//  RDWIN(c+1) issued BEFORE FMA(c); lgkmcnt(3) leaves those 3 reads
//  outstanding and guarantees window(c) (read last step) has landed.
//  Then: FMA(c); reissue x1(c+2) into p##C; DMA(c+4) into slot Q (its
//  read R(c) is complete per lgkmcnt above).
#define PHASE(Q, QN, C, N)                                                  \
    do {                                                                    \
        asm volatile("s_waitcnt vmcnt(3)" ::: "memory");                    \
        RDWIN(QN, N);                                                       \
        asm volatile("s_waitcnt lgkmcnt(3)" ::: "memory");                  \
        FMAS(p##C, w0##C, w1##C, w2##C);                                    \
        p##C = *(const float4*)(x1p + (size_t)(Q + 2) * CH);                \
        PIN();                                                              \
        GLOAD_LDS16(x2p + (size_t)(Q + 4) * CH, xrow(Q) + 4);               \
        PIN();                                                              \
    } while (0)

// Block = 9 waves = one output row (b,h). Wave wi: offset i=wi-4, x2 row
// r=h-i, private 4-deep LDS ring (no main-loop barriers). Read-ahead DS
// pipeline with counted lgkm/vmcnt. x1 in a 2-slot register pipeline
// (8/9 waves hit L1 on x1 -- short latency). Softmax reduction buffer
// aliases the rings (barrier first). Live set ~80 VGPR < 84 cap.
__global__ __launch_bounds__(576)
void corr_softmax_kernel(const float* __restrict__ x1,
                         const float* __restrict__ x2,
                         float* __restrict__ out)
{
    __shared__ __align__(16) float smem[9 * 4 * ROWF];  // 38016 B

    const int tid = threadIdx.x;
    const int wi  = tid >> 6;   // 0..8
    const int t   = tid & 63;
    // XCD-aware swizzle (kept since R2: FETCH 294->~72 MB)
    const int bid = blockIdx.x;
    const int bh  = (bid & 7) * 128 + (bid >> 3);
    const int b   = bh >> 8;
    const int h   = bh & 255;

    float acc[9][4];
#pragma unroll
    for (int jj = 0; jj < 9; ++jj)
#pragma unroll
        for (int s = 0; s < 4; ++s)
            acc[jj][s] = 0.f;

    const int r = h + 4 - wi;  // x2 row = h - i
    if ((unsigned)r < (unsigned)Hc) {
        // zero the 4-float pads at both ends of each ring slot
        if (t < 8) {
            const int idx = (t < 4) ? t : (256 + t);  // 0..3 / 260..263
#pragma unroll
            for (int q = 0; q < 4; ++q) xrow(q)[idx] = 0.f;
        }

        const float* x1p = x1 + (size_t)b * Cc * CH + (size_t)h * Wc + 4 * t;
        const float* x2p = x2 + (size_t)b * Cc * CH + (size_t)r * Wc + 4 * t;

        float4 pa, pb;
        float4 w0a, w1a, w2a, w0b, w1b, w2b;

        // prologue -- issue order builds the steady-state VMEM queue
        // [DMA(1), x1(0), DMA(2), x1(1), DMA(3)] after the vmcnt(5):
        GLOAD_LDS16(x2p + 0 * (size_t)CH, xrow(0) + 4); PIN();
        GLOAD_LDS16(x2p + 1 * (size_t)CH, xrow(1) + 4); PIN();
        pa = *(const float4*)(x1p + 0 * (size_t)CH);    PIN();
        GLOAD_LDS16(x2p + 2 * (size_t)CH, xrow(2) + 4); PIN();
        pb = *(const float4*)(x1p + 1 * (size_t)CH);    PIN();
        GLOAD_LDS16(x2p + 3 * (size_t)CH, xrow(3) + 4); PIN();
        asm volatile("s_waitcnt vmcnt(5)" ::: "memory");  // DMA(0) done
        RDWIN(0, a);                                      // window(0)

#pragma unroll 1
        for (int it = 0; it < 15; ++it) {   // steps c = 4it .. 4it+3
            PHASE(0, 1, a, b);
            PHASE(1, 2, b, a);
            PHASE(2, 3, a, b);
            PHASE(3, 0, b, a);
            x1p += 4 * (size_t)CH;
            x2p += 4 * (size_t)CH;
        }
        // tail: c=60..63 (x1p at channel 60), decreasing counted drains
        // c=60
        asm volatile("s_waitcnt vmcnt(3)" ::: "memory");
        RDWIN(1, b);
        asm volatile("s_waitcnt lgkmcnt(3)" ::: "memory");
        FMAS(pa, w0a, w1a, w2a);
        pa = *(const float4*)(x1p + (size_t)2 * CH); PIN();
        // c=61
        asm volatile("s_waitcnt vmcnt(2)" ::: "memory");
        RDWIN(2, a);
        asm volatile("s_waitcnt lgkmcnt(3)" ::: "memory");
        FMAS(pb, w0b, w1b, w2b);
        pb = *(const float4*)(x1p + (size_t)3 * CH); PIN();
        // c=62
        asm volatile("s_waitcnt vmcnt(1)" ::: "memory");
        RDWIN(3, b);
        asm volatile("s_waitcnt lgkmcnt(3)" ::: "memory");
        FMAS(pa, w0a, w1a, w2a);
        // c=63
        asm volatile("s_waitcnt vmcnt(0)" ::: "memory");
        asm volatile("s_waitcnt lgkmcnt(0)" ::: "memory");
        FMAS(pb, w0b, w1b, w2b);
    }

    // rings dead from here; the reduction buffer aliases smem
    __syncthreads();

    // ---- softmax over 81 channels, reduced across the 9 waves ----
    float m0, m1, m2, m3;
    {
        float v0 = acc[0][0], v1 = acc[0][1], v2 = acc[0][2], v3 = acc[0][3];
#pragma unroll
        for (int jj = 1; jj < 9; ++jj) {
            v0 = fmaxf(v0, acc[jj][0]);
            v1 = fmaxf(v1, acc[jj][1]);
            v2 = fmaxf(v2, acc[jj][2]);
            v3 = fmaxf(v3, acc[jj][3]);
        }
        m0 = v0; m1 = v1; m2 = v2; m3 = v3;
    }
    *(float4*)(smem + wi * 256 + 4 * t) = make_float4(m0, m1, m2, m3);
    __syncthreads();

    float M0, M1, M2, M3;
    {
        float4 q = *(const float4*)(smem + 4 * t);
        M0 = q.x; M1 = q.y; M2 = q.z; M3 = q.w;
#pragma unroll
        for (int w2 = 1; w2 < 9; ++w2) {
            float4 qq = *(const float4*)(smem + w2 * 256 + 4 * t);
            M0 = fmaxf(M0, qq.x); M1 = fmaxf(M1, qq.y);
            M2 = fmaxf(M2, qq.z); M3 = fmaxf(M3, qq.w);
        }
    }

    float s0 = 0.f, s1 = 0.f, s2 = 0.f, s3 = 0.f;
#pragma unroll
    for (int jj = 0; jj < 9; ++jj) {
        acc[jj][0] = __expf(acc[jj][0] - M0); s0 += acc[jj][0];
        acc[jj][1] = __expf(acc[jj][1] - M1); s1 += acc[jj][1];
        acc[jj][2] = __expf(acc[jj][2] - M2); s2 += acc[jj][2];
        acc[jj][3] = __expf(acc[jj][3] - M3); s3 += acc[jj][3];
    }
    __syncthreads();  // everyone done reading maxes
    *(float4*)(smem + wi * 256 + 4 * t) = make_float4(s0, s1, s2, s3);
    __syncthreads();

    float S0, S1, S2, S3;
    {
        float4 q = *(const float4*)(smem + 4 * t);
        S0 = q.x; S1 = q.y; S2 = q.z; S3 = q.w;
#pragma unroll
        for (int w2 = 1; w2 < 9; ++w2) {
            float4 qq = *(const float4*)(smem + w2 * 256 + 4 * t);
            S0 += qq.x; S1 += qq.y; S2 += qq.z; S3 += qq.w;
        }
    }
    const float i0 = 1.0f / S0, i1 = 1.0f / S1, i2 = 1.0f / S2, i3 = 1.0f / S3;

    // k = (9*(wi-4) + (jj-4)) mod 81 = 9*wi + jj + 41 (mod 81)
    float* outp = out + (size_t)b * Dc * CH + (size_t)h * Wc + 4 * t;
#pragma unroll
    for (int jj = 0; jj < 9; ++jj) {
        int kc = 9 * wi + jj + 41;
        if (kc >= 81) kc -= 81;
        float4 o = make_float4(acc[jj][0] * i0, acc[jj][1] * i1,
                               acc[jj][2] * i2, acc[jj][3] * i3);
        *(float4*)(outp + (size_t)kc * CH) = o;
    }
}

extern "C" void kernel_launch(void* const* d_in, const int* in_sizes, int n_in,
                              void* d_out, int out_size, void* d_ws, size_t ws_size,
                              hipStream_t stream) {
    (void)in_sizes; (void)n_in; (void)d_ws; (void)ws_size; (void)out_size;
    const float* x1 = (const float*)d_in[0];
    const float* x2 = (const float*)d_in[1];
    float* out = (float*)d_out;
    dim3 grid(Bc * Hc);   // 1024 blocks: one per (b, h) row
    dim3 block(576);      // 9 waves
    hipLaunchKernelGGL(corr_softmax_kernel, grid, block, 0, stream, x1, x2, out);
}

// Round 9
// 89.233 us; speedup vs baseline: 1.1029x; 1.1029x over previous
//
#include <hip/hip_runtime.h>
#include <stddef.h>

namespace {
constexpr int Hc = 256, Wc = 256, Cc = 64, Bc = 4, Dc = 81;
constexpr int CH = Hc * Wc;  // channel stride in floats
}

#define PIN() asm volatile("" ::: "memory")

// whole-wave lane shifts (gfx9 DPP, valid on CDNA4). bound_ctrl=1 -> lanes
// with no source (lane 0 for shr, lane 63 for shl) read 0 == zero-pad.
// wave_shr:1 (0x138): lane n <- lane n-1.  wave_shl:1 (0x130): lane n <- lane n+1.
#define DPPL(x) __builtin_amdgcn_update_dpp(0, (x), 0x138, 0xf, 0xf, true)
#define DPPR(x) __builtin_amdgcn_update_dpp(0, (x), 0x130, 0xf, 0xf, true)

// 36 FMAs: pixel w=4t+s, offset j=jj-4 -> window col 4t-4+(s-jj+8)
#define FMAS(P, A, Bv, Cv)                                                  \
    do {                                                                    \
        const float w_[12] = {A.x,  A.y,  A.z,  A.w,  Bv.x, Bv.y,           \
                              Bv.z, Bv.w, Cv.x, Cv.y, Cv.z, Cv.w};          \
        const float pv_[4] = {P.x, P.y, P.z, P.w};                          \
        _Pragma("unroll") for (int jj = 0; jj < 9; ++jj)                    \
            _Pragma("unroll") for (int s = 0; s < 4; ++s)                   \
                acc[jj][s] += pv_[s] * w_[s - jj + 8];                      \
    } while (0)

// build the 12-float window from stage S's own-quad via DPP, then FMA
#define WINFMA(S)                                                           \
    do {                                                                    \
        const int b0_ = __float_as_int(xq##S.x);                            \
        const int b1_ = __float_as_int(xq##S.y);                            \
        const int b2_ = __float_as_int(xq##S.z);                            \
        const int b3_ = __float_as_int(xq##S.w);                            \
        float4 L_, R_;                                                      \
        L_.x = __int_as_float(DPPL(b0_)); L_.y = __int_as_float(DPPL(b1_)); \
        L_.z = __int_as_float(DPPL(b2_)); L_.w = __int_as_float(DPPL(b3_)); \
        R_.x = __int_as_float(DPPR(b0_)); R_.y = __int_as_float(DPPR(b1_)); \
        R_.z = __int_as_float(DPPR(b2_)); R_.w = __int_as_float(DPPR(b3_)); \
        FMAS(p##S, L_, xq##S, R_);                                          \
    } while (0)

#define STEP(S, VM)                                                         \
    do {                                                                    \
        asm volatile("s_waitcnt vmcnt(" #VM ")" ::: "memory");              \
        WINFMA(S);                                                          \
    } while (0)

// issue the (x2, x1) pair for channel base+OFF into stage S
#define ISSUE(S, OFF)                                                       \
    do {                                                                    \
        xq##S = *(const float4*)(x2p + (size_t)(OFF) * CH);                 \
        p##S  = *(const float4*)(x1p + (size_t)(OFF) * CH);                 \
        PIN();                                                              \
    } while (0)

// Block = 9 waves = one output row (b,h). Wave wi: offset i=wi-4, x2 row
// r=h+4-wi. Lane t: pixels 4t..4t+3. Per channel: 2 coalesced dwordx4
// loads + 8 v_mov_dpp + 36 FMAs. NO LDS in the main loop (window neighbor
// quads come from DPP wave_shr/shl with free edge zero-fill). Depth-3 pair
// pipeline, counted vmcnt(4): queue 6 deep, completes this step's pair.
// Live set ~80 VGPR < the backend's observed 84 cap (R4-R6).
__global__ __launch_bounds__(576)
void corr_softmax_kernel(const float* __restrict__ x1,
                         const float* __restrict__ x2,
                         float* __restrict__ out)
{
    __shared__ float red[9][Wc];  // 9 KB softmax reduction only

    const int tid = threadIdx.x;
    const int wi  = tid >> 6;   // 0..8
    const int t   = tid & 63;
    // XCD-aware swizzle (kept since R2: FETCH 294->~72 MB)
    const int bid = blockIdx.x;
    const int bh  = (bid & 7) * 128 + (bid >> 3);
    const int b   = bh >> 8;
    const int h   = bh & 255;

    float acc[9][4];
#pragma unroll
    for (int jj = 0; jj < 9; ++jj)
#pragma unroll
        for (int s = 0; s < 4; ++s)
            acc[jj][s] = 0.f;

    const int r = h + 4 - wi;  // x2 row = h - i; OOB rows correlate to 0
    if ((unsigned)r < (unsigned)Hc) {
        const float* x1p = x1 + (size_t)b * Cc * CH + (size_t)h * Wc + 4 * t;
        const float* x2p = x2 + (size_t)b * Cc * CH + (size_t)r * Wc + 4 * t;

        float4 xq0, p0, xq1, p1, xq2, p2;
        // prologue: pairs for channels 0..2 -> queue [x2_0,x1_0,...,x1_2]
        ISSUE(0, 0);
        ISSUE(1, 1);
        ISSUE(2, 2);

#pragma unroll 1
        for (int it = 0; it < 20; ++it) {   // channels 3it .. 3it+2
            STEP(0, 4); ISSUE(0, 3);
            STEP(1, 4); ISSUE(1, 4);
            STEP(2, 4); ISSUE(2, 5);
            x1p += 3 * (size_t)CH;
            x2p += 3 * (size_t)CH;
        }
        // tail: channels 60..63 (base at 60); pair 63 into stage 0
        STEP(0, 4); ISSUE(0, 3);   // ch 60, issue 63
        STEP(1, 4);                // ch 61
        STEP(2, 2);                // ch 62
        STEP(0, 0);                // ch 63
    }

    // ---- softmax over 81 channels, reduced across the 9 waves ----
    float m0, m1, m2, m3;
    {
        float v0 = acc[0][0], v1 = acc[0][1], v2 = acc[0][2], v3 = acc[0][3];
#pragma unroll
        for (int jj = 1; jj < 9; ++jj) {
            v0 = fmaxf(v0, acc[jj][0]);
            v1 = fmaxf(v1, acc[jj][1]);
            v2 = fmaxf(v2, acc[jj][2]);
            v3 = fmaxf(v3, acc[jj][3]);
        }
        m0 = v0; m1 = v1; m2 = v2; m3 = v3;
    }
    *reinterpret_cast<float4*>(&red[wi][4 * t]) = make_float4(m0, m1, m2, m3);
    __syncthreads();

    float M0, M1, M2, M3;
    {
        float4 q = *reinterpret_cast<const float4*>(&red[0][4 * t]);
        M0 = q.x; M1 = q.y; M2 = q.z; M3 = q.w;
#pragma unroll
        for (int w2 = 1; w2 < 9; ++w2) {
            float4 qq = *reinterpret_cast<const float4*>(&red[w2][4 * t]);
            M0 = fmaxf(M0, qq.x); M1 = fmaxf(M1, qq.y);
            M2 = fmaxf(M2, qq.z); M3 = fmaxf(M3, qq.w);
        }
    }

    float s0 = 0.f, s1 = 0.f, s2 = 0.f, s3 = 0.f;
#pragma unroll
    for (int jj = 0; jj < 9; ++jj) {
        acc[jj][0] = __expf(acc[jj][0] - M0); s0 += acc[jj][0];
        acc[jj][1] = __expf(acc[jj][1] - M1); s1 += acc[jj][1];
        acc[jj][2] = __expf(acc[jj][2] - M2); s2 += acc[jj][2];
        acc[jj][3] = __expf(acc[jj][3] - M3); s3 += acc[jj][3];
    }
    __syncthreads();  // everyone done reading maxes
    *reinterpret_cast<float4*>(&red[wi][4 * t]) = make_float4(s0, s1, s2, s3);
    __syncthreads();

    float S0, S1, S2, S3;
    {
        float4 q = *reinterpret_cast<const float4*>(&red[0][4 * t]);
        S0 = q.x; S1 = q.y; S2 = q.z; S3 = q.w;
#pragma unroll
        for (int w2 = 1; w2 < 9; ++w2) {
            float4 qq = *reinterpret_cast<const float4*>(&red[w2][4 * t]);
            S0 += qq.x; S1 += qq.y; S2 += qq.z; S3 += qq.w;
        }
    }
    const float i0 = 1.0f / S0, i1 = 1.0f / S1, i2 = 1.0f / S2, i3 = 1.0f / S3;

    // k = (9*(wi-4) + (jj-4)) mod 81 = 9*wi + jj + 41 (mod 81)
    float* outp = out + (size_t)b * Dc * CH + (size_t)h * Wc + 4 * t;
#pragma unroll
    for (int jj = 0; jj < 9; ++jj) {
        int kc = 9 * wi + jj + 41;
        if (kc >= 81) kc -= 81;
        float4 o = make_float4(acc[jj][0] * i0, acc[jj][1] * i1,
                               acc[jj][2] * i2, acc[jj][3] * i3);
        *reinterpret_cast<float4*>(outp + (size_t)kc * CH) = o;
    }
}

extern "C" void kernel_launch(void* const* d_in, const int* in_sizes, int n_in,
                              void* d_out, int out_size, void* d_ws, size_t ws_size,
                              hipStream_t stream) {
    (void)in_sizes; (void)n_in; (void)d_ws; (void)ws_size; (void)out_size;
    const float* x1 = (const float*)d_in[0];
    const float* x2 = (const float*)d_in[1];
    float* out = (float*)d_out;
    dim3 grid(Bc * Hc);   // 1024 blocks: one per (b, h) row
    dim3 block(576);      // 9 waves
    hipLaunchKernelGGL(corr_softmax_kernel, grid, block, 0, stream, x1, x2, out);
}

// Round 10
// 83.534 us; speedup vs baseline: 1.1782x; 1.0682x over previous
//
#include <hip/hip_runtime.h>
#include <stddef.h>

namespace {
constexpr int Hc = 256, Wc = 256, Cc = 64, Bc = 4, Dc = 81;
constexpr int CH = Hc * Wc;  // channel stride in floats
}

#define PIN() asm volatile("" ::: "memory")
#define VMW(N) asm volatile("s_waitcnt vmcnt(" #N ")" ::: "memory")

// async global->LDS DMA: per-lane global src, wave-uniform LDS dest + lane*16
#define GLOAD_LDS16(g, l)                                                   \
    __builtin_amdgcn_global_load_lds(                                       \
        (const __attribute__((address_space(1))) void*)(g),                 \
        (__attribute__((address_space(3))) void*)(l), 16, 0, 0)

// whole-wave lane shifts (DPP). bound_ctrl=1 -> edge lanes read 0 == zero-pad
#define DPPL(x) __builtin_amdgcn_update_dpp(0, (x), 0x138, 0xf, 0xf, true)
#define DPPR(x) __builtin_amdgcn_update_dpp(0, (x), 0x130, 0xf, 0xf, true)

// 36 FMAs: pixel w=4t+s, offset j=jj-4 -> window col idx s-jj+8
#define FMAS(P, A, Bv, Cv)                                                  \
    do {                                                                    \
        const float w_[12] = {A.x,  A.y,  A.z,  A.w,  Bv.x, Bv.y,           \
                              Bv.z, Bv.w, Cv.x, Cv.y, Cv.z, Cv.w};          \
        const float pv_[4] = {P.x, P.y, P.z, P.w};                          \
        _Pragma("unroll") for (int jj = 0; jj < 9; ++jj)                    \
            _Pragma("unroll") for (int s = 0; s < 4; ++s)                   \
                acc[jj][s] += pv_[s] * w_[s - jj + 8];                      \
    } while (0)

// window from x2 stage S via DPP, FMA against x1 quad P
#define FM(S, P)                                                            \
    do {                                                                    \
        const int b0_ = __float_as_int(xq##S.x);                            \
        const int b1_ = __float_as_int(xq##S.y);                            \
        const int b2_ = __float_as_int(xq##S.z);                            \
        const int b3_ = __float_as_int(xq##S.w);                            \
        float4 L_, R_;                                                      \
        L_.x = __int_as_float(DPPL(b0_)); L_.y = __int_as_float(DPPL(b1_)); \
        L_.z = __int_as_float(DPPL(b2_)); L_.w = __int_as_float(DPPL(b3_)); \
        R_.x = __int_as_float(DPPR(b0_)); R_.y = __int_as_float(DPPR(b1_)); \
        R_.z = __int_as_float(DPPR(b2_)); R_.w = __int_as_float(DPPR(b3_)); \
        FMAS(P, L_, xq##S, R_);                                             \
    } while (0)

#define RD1(N, RP) N = *(const float4*)(RP)     // x1 quad from LDS (b128)
#define ISX(T, OFF)                                                         \
    do {                                                                    \
        xq##T = *(const float4*)(x2p + (size_t)(OFF) * CH);                 \
        PIN();                                                              \
    } while (0)

// One 8-channel group (channels rel. 0..7 of x2p/x1g). DMA stages the NEXT
// group's x1 rows into NXT while computing from CUR. vmcnt ladder derived
// from queue [x2+0,x2+1,x2+2] + DMA(newest): 3,3,3 then 2... Raw s_barrier
// (no vmcnt drain!) releases NXT to readers; each wave's own s=3 VMW(2)
// retired its DMA before it reaches the barrier.
#define GROUPN(CUR, NXT)                                                    \
    do {                                                                    \
        GLOAD_LDS16(x1g + (size_t)(8 + mwi) * CH, (NXT) + wi * 256);        \
        PIN();                                                              \
        RD1(xb, (CUR) + 1 * 256 + 4 * t); VMW(3); FM(0, xa); ISX(3, 3);     \
        RD1(xa, (CUR) + 2 * 256 + 4 * t); VMW(3); FM(1, xb); ISX(0, 4);     \
        RD1(xb, (CUR) + 3 * 256 + 4 * t); VMW(3); FM(2, xa); ISX(1, 5);     \
        RD1(xa, (CUR) + 4 * 256 + 4 * t); VMW(2); FM(3, xb); ISX(2, 6);     \
        RD1(xb, (CUR) + 5 * 256 + 4 * t); VMW(2); FM(0, xa); ISX(3, 7);     \
        RD1(xa, (CUR) + 6 * 256 + 4 * t); VMW(2); FM(1, xb); ISX(0, 8);     \
        RD1(xb, (CUR) + 7 * 256 + 4 * t); VMW(2); FM(2, xa); ISX(1, 9);     \
        VMW(2); FM(3, xb); ISX(2, 10);                                      \
        PIN(); __builtin_amdgcn_s_barrier(); PIN();                         \
        RD1(xa, (NXT) + 4 * t);                                             \
        x2p += (size_t)8 * CH; x1g += (size_t)8 * CH;                       \
    } while (0)

// Block = 9 waves = one output row (b,h). Wave wi: offset i=wi-4, x2 row
// r=h+4-wi (clamped; invalid waves zero acc post-loop). Lane t: pixels
// 4t..4t+3. x2 windows: own dwordx4 + DPP neighbor shifts (no LDS). x1: the
// row all 9 waves share is DMA'd to LDS once per 8-channel group (1 KB per
// group per block) and served by the DS pipe -- halves L1 port traffic.
__global__ __launch_bounds__(576)
void corr_softmax_kernel(const float* __restrict__ x1,
                         const float* __restrict__ x2,
                         float* __restrict__ out)
{
    __shared__ __align__(16) float bufA[9 * 256];  // 9 KB x1 slab (dbuf A)
    __shared__ __align__(16) float bufB[9 * 256];  // 9 KB x1 slab (dbuf B)
    __shared__ __align__(16) float red[9 * 256];   // 9 KB softmax reduction

    const int tid = threadIdx.x;
    const int wi  = tid >> 6;   // 0..8
    const int t   = tid & 63;
    const int mwi = (wi < 8) ? wi : 7;  // wave 8: dummy DMA (slot 8, unread)
    // XCD-aware swizzle (kept since R2: FETCH 294->~72 MB)
    const int bid = blockIdx.x;
    const int bh  = (bid & 7) * 128 + (bid >> 3);
    const int b   = bh >> 8;
    const int h   = bh & 255;

    float acc[9][4];
#pragma unroll
    for (int jj = 0; jj < 9; ++jj)
#pragma unroll
        for (int s = 0; s < 4; ++s)
            acc[jj][s] = 0.f;

    const int r  = h + 4 - wi;                       // x2 row = h - i
    const int rr = (r < 0) ? 0 : ((r > 255) ? 255 : r);  // clamped (uniform path)

    const float* x2p = x2 + (size_t)b * Cc * CH + (size_t)rr * Wc + 4 * t;
    const float* x1g = x1 + (size_t)b * Cc * CH + (size_t)h * Wc + 4 * t;

    float4 xq0, xq1, xq2, xq3, xa, xb;

    // prologue: stage group-0 x1 rows into bufA; prime x2 stages 0..2.
    // queue after issues: [DMA0, x2_0, x2_1, x2_2] -> VMW(3) retires DMA0.
    GLOAD_LDS16(x1g + (size_t)mwi * CH, bufA + wi * 256);
    PIN();
    ISX(0, 0); ISX(1, 1); ISX(2, 2);
    VMW(3);
    PIN(); __builtin_amdgcn_s_barrier(); PIN();
    RD1(xa, bufA + 4 * t);   // x1 channel 0

#pragma unroll 1
    for (int g = 0; g < 3; ++g) {   // groups 0..5 (channels 0..47)
        GROUPN(bufA, bufB);
        GROUPN(bufB, bufA);
    }
    GROUPN(bufA, bufB);             // group 6 (48..55), stages tail rows

    // tail group: channels 56..63 from bufB, no DMA, drain 2,2,2,2,2,2,1,0
    RD1(xb, bufB + 1 * 256 + 4 * t); VMW(2); FM(0, xa); ISX(3, 3);
    RD1(xa, bufB + 2 * 256 + 4 * t); VMW(2); FM(1, xb); ISX(0, 4);
    RD1(xb, bufB + 3 * 256 + 4 * t); VMW(2); FM(2, xa); ISX(1, 5);
    RD1(xa, bufB + 4 * 256 + 4 * t); VMW(2); FM(3, xb); ISX(2, 6);
    RD1(xb, bufB + 5 * 256 + 4 * t); VMW(2); FM(0, xa); ISX(3, 7);
    RD1(xa, bufB + 6 * 256 + 4 * t); VMW(2); FM(1, xb);
    RD1(xb, bufB + 7 * 256 + 4 * t); VMW(1); FM(2, xa);
    VMW(0); FM(3, xb);

    // invalid x2 rows (out of [0,256)) correlate to zero: wipe their acc
    if ((unsigned)r >= (unsigned)Hc) {
#pragma unroll
        for (int jj = 0; jj < 9; ++jj)
#pragma unroll
            for (int s = 0; s < 4; ++s)
                acc[jj][s] = 0.f;
    }

    __syncthreads();  // full drain OK here; rings/slabs dead

    // ---- softmax over 81 channels, reduced across the 9 waves ----
    float m0, m1, m2, m3;
    {
        float v0 = acc[0][0], v1 = acc[0][1], v2 = acc[0][2], v3 = acc[0][3];
#pragma unroll
        for (int jj = 1; jj < 9; ++jj) {
            v0 = fmaxf(v0, acc[jj][0]);
            v1 = fmaxf(v1, acc[jj][1]);
            v2 = fmaxf(v2, acc[jj][2]);
            v3 = fmaxf(v3, acc[jj][3]);
        }
        m0 = v0; m1 = v1; m2 = v2; m3 = v3;
    }
    *(float4*)(red + wi * 256 + 4 * t) = make_float4(m0, m1, m2, m3);
    __syncthreads();

    float M0, M1, M2, M3;
    {
        float4 q = *(const float4*)(red + 4 * t);
        M0 = q.x; M1 = q.y; M2 = q.z; M3 = q.w;
#pragma unroll
        for (int w2 = 1; w2 < 9; ++w2) {
            float4 qq = *(const float4*)(red + w2 * 256 + 4 * t);
            M0 = fmaxf(M0, qq.x); M1 = fmaxf(M1, qq.y);
            M2 = fmaxf(M2, qq.z); M3 = fmaxf(M3, qq.w);
        }
    }

    float s0 = 0.f, s1 = 0.f, s2 = 0.f, s3 = 0.f;
#pragma unroll
    for (int jj = 0; jj < 9; ++jj) {
        acc[jj][0] = __expf(acc[jj][0] - M0); s0 += acc[jj][0];
        acc[jj][1] = __expf(acc[jj][1] - M1); s1 += acc[jj][1];
        acc[jj][2] = __expf(acc[jj][2] - M2); s2 += acc[jj][2];
        acc[jj][3] = __expf(acc[jj][3] - M3); s3 += acc[jj][3];
    }
    __syncthreads();  // everyone done reading maxes
    *(float4*)(red + wi * 256 + 4 * t) = make_float4(s0, s1, s2, s3);
    __syncthreads();

    float S0, S1, S2, S3;
    {
        float4 q = *(const float4*)(red + 4 * t);
        S0 = q.x; S1 = q.y; S2 = q.z; S3 = q.w;
#pragma unroll
        for (int w2 = 1; w2 < 9; ++w2) {
            float4 qq = *(const float4*)(red + w2 * 256 + 4 * t);
            S0 += qq.x; S1 += qq.y; S2 += qq.z; S3 += qq.w;
        }
    }
    const float i0 = 1.0f / S0, i1 = 1.0f / S1, i2 = 1.0f / S2, i3 = 1.0f / S3;

    // k = (9*(wi-4) + (jj-4)) mod 81 = 9*wi + jj + 41 (mod 81)
    float* outp = out + (size_t)b * Dc * CH + (size_t)h * Wc + 4 * t;
#pragma unroll
    for (int jj = 0; jj < 9; ++jj) {
        int kc = 9 * wi + jj + 41;
        if (kc >= 81) kc -= 81;
        float4 o = make_float4(acc[jj][0] * i0, acc[jj][1] * i1,
                               acc[jj][2] * i2, acc[jj][3] * i3);
        *(float4*)(outp + (size_t)kc * CH) = o;
    }
}

extern "C" void kernel_launch(void* const* d_in, const int* in_sizes, int n_in,
                              void* d_out, int out_size, void* d_ws, size_t ws_size,
                              hipStream_t stream) {
    (void)in_sizes; (void)n_in; (void)d_ws; (void)ws_size; (void)out_size;
    const float* x1 = (const float*)d_in[0];
    const float* x2 = (const float*)d_in[1];
    float* out = (float*)d_out;
    dim3 grid(Bc * Hc);   // 1024 blocks: one per (b, h) row
    dim3 block(576);      // 9 waves
    hipLaunchKernelGGL(corr_softmax_kernel, grid, block, 0, stream, x1, x2, out);
}

// Round 11
// 82.268 us; speedup vs baseline: 1.1963x; 1.0154x over previous
//
#include <hip/hip_runtime.h>
#include <stddef.h>

namespace {
constexpr int Hc = 256, Wc = 256, Cc = 64, Bc = 4, Dc = 81;
constexpr int CH = Hc * Wc;  // channel stride in floats
}

#define PIN() asm volatile("" ::: "memory")
#define VMW(N) asm volatile("s_waitcnt vmcnt(" #N ")" ::: "memory")

// async global->LDS DMA: per-lane global src, wave-uniform LDS dest + lane*16
#define GLOAD_LDS16(g, l)                                                   \
    __builtin_amdgcn_global_load_lds(                                       \
        (const __attribute__((address_space(1))) void*)(g),                 \
        (__attribute__((address_space(3))) void*)(l), 16, 0, 0)

// whole-wave lane shifts (DPP). bound_ctrl=1 -> edge lanes read 0 == zero-pad
#define DPPL(x) __builtin_amdgcn_update_dpp(0, (x), 0x138, 0xf, 0xf, true)
#define DPPR(x) __builtin_amdgcn_update_dpp(0, (x), 0x130, 0xf, 0xf, true)

// 36 FMAs: pixel w=4t+s, offset j=jj-4 -> window col idx s-jj+8
#define FMAS(P, A, Bv, Cv)                                                  \
    do {                                                                    \
        const float w_[12] = {A.x,  A.y,  A.z,  A.w,  Bv.x, Bv.y,           \
                              Bv.z, Bv.w, Cv.x, Cv.y, Cv.z, Cv.w};          \
        const float pv_[4] = {P.x, P.y, P.z, P.w};                          \
        _Pragma("unroll") for (int jj = 0; jj < 9; ++jj)                    \
            _Pragma("unroll") for (int s = 0; s < 4; ++s)                   \
                acc[jj][s] += pv_[s] * w_[s - jj + 8];                      \
    } while (0)

// window from x2 stage S via DPP, FMA against x1 quad P
#define FM(S, P)                                                            \
    do {                                                                    \
        const int b0_ = __float_as_int(xq##S.x);                            \
        const int b1_ = __float_as_int(xq##S.y);                            \
        const int b2_ = __float_as_int(xq##S.z);                            \
        const int b3_ = __float_as_int(xq##S.w);                            \
        float4 L_, R_;                                                      \
        L_.x = __int_as_float(DPPL(b0_)); L_.y = __int_as_float(DPPL(b1_)); \
        L_.z = __int_as_float(DPPL(b2_)); L_.w = __int_as_float(DPPL(b3_)); \
        R_.x = __int_as_float(DPPR(b0_)); R_.y = __int_as_float(DPPR(b1_)); \
        R_.z = __int_as_float(DPPR(b2_)); R_.w = __int_as_float(DPPR(b3_)); \
        FMAS(P, L_, xq##S, R_);                                             \
    } while (0)

#define RD1(N, RP) N = *(const float4*)(RP)     // x1 quad from LDS (b128)
#define ISX(T, OFF)                                                         \
    do {                                                                    \
        xq##T = *(const float4*)(x2p + (size_t)(OFF) * CH);                 \
        PIN();                                                              \
    } while (0)

// One 8-channel group (base c0; stage s = channel & 7). On entry the VMEM
// queue holds [X(c0)..X(c0+7)]; DMA(next x1 slab) is issued, then each step
// does VMW(8) (retire exactly the x2 this step needs), FMA, and reissues
// that stage for channel c0+8+k. Final VMW(8) retires the DMA before the
// barrier releases NXT to readers. Prefetch distance: 8 channel-steps.
#define GROUPN(CUR, NXT)                                                    \
    do {                                                                    \
        GLOAD_LDS16(x1g + (size_t)(8 + mwi) * CH, (NXT) + wi * 256);        \
        PIN();                                                              \
        RD1(xb, (CUR) + 1 * 256 + 4 * t); VMW(8); FM(0, xa); ISX(0, 8);     \
        RD1(xa, (CUR) + 2 * 256 + 4 * t); VMW(8); FM(1, xb); ISX(1, 9);     \
        RD1(xb, (CUR) + 3 * 256 + 4 * t); VMW(8); FM(2, xa); ISX(2, 10);    \
        RD1(xa, (CUR) + 4 * 256 + 4 * t); VMW(8); FM(3, xb); ISX(3, 11);    \
        RD1(xb, (CUR) + 5 * 256 + 4 * t); VMW(8); FM(4, xa); ISX(4, 12);    \
        RD1(xa, (CUR) + 6 * 256 + 4 * t); VMW(8); FM(5, xb); ISX(5, 13);    \
        RD1(xb, (CUR) + 7 * 256 + 4 * t); VMW(8); FM(6, xa); ISX(6, 14);    \
        VMW(8); FM(7, xb); ISX(7, 15);                                      \
        VMW(8);                                                             \
        PIN(); __builtin_amdgcn_s_barrier(); PIN();                         \
        RD1(xa, (NXT) + 4 * t);                                             \
        x2p += (size_t)8 * CH; x1g += (size_t)8 * CH;                       \
    } while (0)

// Block = 9 waves = one output row (b,h). Wave wi: offset i=wi-4, x2 row
// r=h+4-wi (clamped; invalid waves zero acc post-loop). Lane t: pixels
// 4t..4t+3. x2 windows: own dwordx4 + DPP neighbor shifts. x1 row shared by
// all 9 waves: DMA'd to an LDS slab once per 8-channel group (DS pipe, not
// L1 port). 8 x2 stages in flight -> ~700+ cy latency coverage per wave.
// Live set ~76 VGPR (R10 measured 60 with 4 stages; +16) < ~84 cap.
__global__ __launch_bounds__(576)
void corr_softmax_kernel(const float* __restrict__ x1,
                         const float* __restrict__ x2,
                         float* __restrict__ out)
{
    __shared__ __align__(16) float bufA[9 * 256];  // x1 slab dbuf A (aliases red)
    __shared__ __align__(16) float bufB[9 * 256];  // x1 slab dbuf B

    const int tid = threadIdx.x;
    const int wi  = tid >> 6;   // 0..8
    const int t   = tid & 63;
    const int mwi = (wi < 8) ? wi : 7;  // wave 8: dummy DMA into unread slot 8
    // XCD-aware swizzle (kept since R2: FETCH 294->~72 MB)
    const int bid = blockIdx.x;
    const int bh  = (bid & 7) * 128 + (bid >> 3);
    const int b   = bh >> 8;
    const int h   = bh & 255;

    float acc[9][4];
#pragma unroll
    for (int jj = 0; jj < 9; ++jj)
#pragma unroll
        for (int s = 0; s < 4; ++s)
            acc[jj][s] = 0.f;

    const int r  = h + 4 - wi;                           // x2 row = h - i
    const int rr = (r < 0) ? 0 : ((r > 255) ? 255 : r);  // clamped, uniform path

    const float* x2p = x2 + (size_t)b * Cc * CH + (size_t)rr * Wc + 4 * t;
    const float* x1g = x1 + (size_t)b * Cc * CH + (size_t)h * Wc + 4 * t;

    float4 xq0, xq1, xq2, xq3, xq4, xq5, xq6, xq7, xa, xb;

    // prologue: DMA group-0 x1 slab; prime x2 stages 0..7.
    // queue [D_A, X0..X7] -> VMW(8) retires D_A; barrier; read x1 ch0.
    GLOAD_LDS16(x1g + (size_t)mwi * CH, bufA + wi * 256);
    PIN();
    ISX(0, 0); ISX(1, 1); ISX(2, 2); ISX(3, 3);
    ISX(4, 4); ISX(5, 5); ISX(6, 6); ISX(7, 7);
    VMW(8);
    PIN(); __builtin_amdgcn_s_barrier(); PIN();
    RD1(xa, bufA + 4 * t);   // x1 channel 0

#pragma unroll 1
    for (int g = 0; g < 3; ++g) {   // groups 0..5 (channels 0..47)
        GROUPN(bufA, bufB);
        GROUPN(bufB, bufA);
    }
    GROUPN(bufA, bufB);             // group 6 (48..55), stages+issues 56..63

    // tail: channels 56..63 from bufB, no DMA/ISX, drain VMW 7..0
    RD1(xb, bufB + 1 * 256 + 4 * t); VMW(7); FM(0, xa);
    RD1(xa, bufB + 2 * 256 + 4 * t); VMW(6); FM(1, xb);
    RD1(xb, bufB + 3 * 256 + 4 * t); VMW(5); FM(2, xa);
    RD1(xa, bufB + 4 * 256 + 4 * t); VMW(4); FM(3, xb);
    RD1(xb, bufB + 5 * 256 + 4 * t); VMW(3); FM(4, xa);
    RD1(xa, bufB + 6 * 256 + 4 * t); VMW(2); FM(5, xb);
    RD1(xb, bufB + 7 * 256 + 4 * t); VMW(1); FM(6, xa);
    VMW(0); FM(7, xb);

    // invalid x2 rows (out of [0,256)) correlate to zero: wipe their acc
    if ((unsigned)r >= (unsigned)Hc) {
#pragma unroll
        for (int jj = 0; jj < 9; ++jj)
#pragma unroll
            for (int s = 0; s < 4; ++s)
                acc[jj][s] = 0.f;
    }

    __syncthreads();  // slabs dead; bufA becomes the reduction buffer
    float* red = bufA;

    // ---- softmax over 81 channels, reduced across the 9 waves ----
    float m0, m1, m2, m3;
    {
        float v0 = acc[0][0], v1 = acc[0][1], v2 = acc[0][2], v3 = acc[0][3];
#pragma unroll
        for (int jj = 1; jj < 9; ++jj) {
            v0 = fmaxf(v0, acc[jj][0]);
            v1 = fmaxf(v1, acc[jj][1]);
            v2 = fmaxf(v2, acc[jj][2]);
            v3 = fmaxf(v3, acc[jj][3]);
        }
        m0 = v0; m1 = v1; m2 = v2; m3 = v3;
    }
    *(float4*)(red + wi * 256 + 4 * t) = make_float4(m0, m1, m2, m3);
    __syncthreads();

    float M0, M1, M2, M3;
    {
        float4 q = *(const float4*)(red + 4 * t);
        M0 = q.x; M1 = q.y; M2 = q.z; M3 = q.w;
#pragma unroll
        for (int w2 = 1; w2 < 9; ++w2) {
            float4 qq = *(const float4*)(red + w2 * 256 + 4 * t);
            M0 = fmaxf(M0, qq.x); M1 = fmaxf(M1, qq.y);
            M2 = fmaxf(M2, qq.z); M3 = fmaxf(M3, qq.w);
        }
    }

    float s0 = 0.f, s1 = 0.f, s2 = 0.f, s3 = 0.f;
#pragma unroll
    for (int jj = 0; jj < 9; ++jj) {
        acc[jj][0] = __expf(acc[jj][0] - M0); s0 += acc[jj][0];
        acc[jj][1] = __expf(acc[jj][1] - M1); s1 += acc[jj][1];
        acc[jj][2] = __expf(acc[jj][2] - M2); s2 += acc[jj][2];
        acc[jj][3] = __expf(acc[jj][3] - M3); s3 += acc[jj][3];
    }
    __syncthreads();  // everyone done reading maxes
    *(float4*)(red + wi * 256 + 4 * t) = make_float4(s0, s1, s2, s3);
    __syncthreads();

    float S0, S1, S2, S3;
    {
        float4 q = *(const float4*)(red + 4 * t);
        S0 = q.x; S1 = q.y; S2 = q.z; S3 = q.w;
#pragma unroll
        for (int w2 = 1; w2 < 9; ++w2) {
            float4 qq = *(const float4*)(red + w2 * 256 + 4 * t);
            S0 += qq.x; S1 += qq.y; S2 += qq.z; S3 += qq.w;
        }
    }
    const float i0 = 1.0f / S0, i1 = 1.0f / S1, i2 = 1.0f / S2, i3 = 1.0f / S3;

    // k = (9*(wi-4) + (jj-4)) mod 81 = 9*wi + jj + 41 (mod 81)
    float* outp = out + (size_t)b * Dc * CH + (size_t)h * Wc + 4 * t;
#pragma unroll
    for (int jj = 0; jj < 9; ++jj) {
        int kc = 9 * wi + jj + 41;
        if (kc >= 81) kc -= 81;
        float4 o = make_float4(acc[jj][0] * i0, acc[jj][1] * i1,
                               acc[jj][2] * i2, acc[jj][3] * i3);
        *(float4*)(outp + (size_t)kc * CH) = o;
    }
}

extern "C" void kernel_launch(void* const* d_in, const int* in_sizes, int n_in,
                              void* d_out, int out_size, void* d_ws, size_t ws_size,
                              hipStream_t stream) {
    (void)in_sizes; (void)n_in; (void)d_ws; (void)ws_size; (void)out_size;
    const float* x1 = (const float*)d_in[0];
    const float* x2 = (const float*)d_in[1];
    float* out = (float*)d_out;
    dim3 grid(Bc * Hc);   // 1024 blocks: one per (b, h) row
    dim3 block(576);      // 9 waves
    hipLaunchKernelGGL(corr_softmax_kernel, grid, block, 0, stream, x1, x2, out);
}

// Round 13
// 70.534 us; speedup vs baseline: 1.3953x; 1.1664x over previous
//
#include <hip/hip_runtime.h>
#include <stddef.h>

namespace {
constexpr int Hc = 256, Wc = 256, Cc = 64, Bc = 4, Dc = 81;
constexpr int CH = Hc * Wc;  // channel stride in floats
}

#define PIN() asm volatile("" ::: "memory")
#define VMW(N) asm volatile("s_waitcnt vmcnt(" #N ")" ::: "memory")

// async global->LDS DMA: per-lane global src, wave-uniform LDS dest + lane*16
#define GLOAD_LDS16(g, l)                                                   \
    __builtin_amdgcn_global_load_lds(                                       \
        (const __attribute__((address_space(1))) void*)(g),                 \
        (__attribute__((address_space(3))) void*)(l), 16, 0, 0)

// whole-wave lane shifts (DPP). bound_ctrl=1 -> edge lanes read 0 == zero-pad
#define DPPL(x) __builtin_amdgcn_update_dpp(0, (x), 0x138, 0xf, 0xf, true)
#define DPPR(x) __builtin_amdgcn_update_dpp(0, (x), 0x130, 0xf, 0xf, true)

// clang's AMDGPU builtins use __fp16 vectors (type letter 'h'), NOT _Float16
typedef __fp16 half2v __attribute__((ext_vector_type(2)));

// pack two f32 (channel pair) into v2f16, as int for DPP transport
static __device__ __forceinline__ int pk2(float a, float b) {
#if __has_builtin(__builtin_amdgcn_cvt_pkrtz)
    half2v h = __builtin_amdgcn_cvt_pkrtz(a, b);
#else
    half2v h; h.x = (__fp16)a; h.y = (__fp16)b;
#endif
    return __builtin_bit_cast(int, h);
}

// f32 += dot2(v2f16, v2f16) -- V_DOT2_F32_F16
static __device__ __forceinline__ float dot2f(int q, int w, float c) {
#if __has_builtin(__builtin_amdgcn_fdot2)
    return __builtin_amdgcn_fdot2(__builtin_bit_cast(half2v, q),
                                  __builtin_bit_cast(half2v, w), c, false);
#else
    half2v a = __builtin_bit_cast(half2v, q);
    half2v b = __builtin_bit_cast(half2v, w);
    return c + (float)a.x * (float)b.x + (float)a.y * (float)b.y;
#endif
}

// One CHANNEL-PAIR step: pack x2 quads (A0=ch e, A1=ch e+1) per pixel, DPP
// neighbor shifts build the packed 12-wide window, pack x1 quads, 36 dot2.
// acc[jj][s] += x1[e..e+1][4t+s] . x2[e..e+1][4t+s-jj+4]
#define FMP(A0, A1, X0, X1)                                                 \
    do {                                                                    \
        const int P0_ = pk2(A0.x, A1.x), P1_ = pk2(A0.y, A1.y);             \
        const int P2_ = pk2(A0.z, A1.z), P3_ = pk2(A0.w, A1.w);             \
        const int w_[12] = {DPPL(P0_), DPPL(P1_), DPPL(P2_), DPPL(P3_),     \
                            P0_,       P1_,       P2_,       P3_,           \
                            DPPR(P0_), DPPR(P1_), DPPR(P2_), DPPR(P3_)};    \
        const int q_[4] = {pk2(X0.x, X1.x), pk2(X0.y, X1.y),                \
                           pk2(X0.z, X1.z), pk2(X0.w, X1.w)};               \
        _Pragma("unroll") for (int jj = 0; jj < 9; ++jj)                    \
            _Pragma("unroll") for (int s = 0; s < 4; ++s)                   \
                acc[jj][s] = dot2f(q_[s], w_[s - jj + 8], acc[jj][s]);      \
    } while (0)

#define ISX(T, OFF)                                                         \
    do {                                                                    \
        xq##T = *(const float4*)(x2p + (size_t)(OFF) * CH);                 \
        PIN();                                                              \
    } while (0)

// read x1 rows RA,RB (channels within group) from slab into 2 quads
#define RDX1(N0, N1, RA, RB, SLAB)                                          \
    do {                                                                    \
        N0 = *(const float4*)((SLAB) + (RA) * 256 + 4 * t);                 \
        N1 = *(const float4*)((SLAB) + (RB) * 256 + 4 * t);                 \
    } while (0)

// One 8-channel group = 4 pair-steps. Stages xq0..3 hold raw f32 x2 quads,
// lookahead 4 channels. vmcnt ladder (derived, D=x1 DMA issued at start):
// start [c0..c3]+D=5; PS0 VMW(3) (c0,c1); PS1 VMW(3) (c2,c3); PS2 VMW(2)
// (D,c4,c5); PS3 VMW(2) (c6,c7) -> D retired before the barrier releases
// NXT slab. x1 quads alternate xc/xn, read one pair ahead (DS pipe).
#define GROUPN(CUR, NXT)                                                    \
    do {                                                                    \
        GLOAD_LDS16(x1g + (size_t)(8 + mwi) * CH, (NXT) + wi * 256);        \
        PIN();                                                              \
        RDX1(xn0, xn1, 2, 3, CUR); VMW(3); FMP(xq0, xq1, xc0, xc1);         \
        ISX(0, 4); ISX(1, 5);                                               \
        RDX1(xc0, xc1, 4, 5, CUR); VMW(3); FMP(xq2, xq3, xn0, xn1);         \
        ISX(2, 6); ISX(3, 7);                                               \
        RDX1(xn0, xn1, 6, 7, CUR); VMW(2); FMP(xq0, xq1, xc0, xc1);         \
        ISX(0, 8); ISX(1, 9);                                               \
        VMW(2); FMP(xq2, xq3, xn0, xn1);                                    \
        ISX(2, 10); ISX(3, 11);                                             \
        PIN(); __builtin_amdgcn_s_barrier(); PIN();                         \
        RDX1(xc0, xc1, 0, 1, NXT);                                          \
        x2p += (size_t)8 * CH; x1g += (size_t)8 * CH;                       \
    } while (0)

// Block = 9 waves = one output row (b,h). Wave wi: offset i=wi-4, x2 row
// r=h+4-wi (clamped; invalid waves zero acc post-loop). Lane t: pixels
// 4t..4t+3. Channels processed in PAIRS packed to f16x2: 36 v_dot2_f32_f16
// per 2 channels (vs 72 v_fma) -- ~1.8x main-loop VALU cut. x2 windows via
// DPP on packed regs; x1 shared row via LDS slab DMA (DS pipe).
__global__ __launch_bounds__(576)
void corr_softmax_kernel(const float* __restrict__ x1,
                         const float* __restrict__ x2,
                         float* __restrict__ out)
{
    __shared__ __align__(16) float bufA[9 * 256];  // x1 slab dbuf A (aliases red)
    __shared__ __align__(16) float bufB[9 * 256];  // x1 slab dbuf B

    const int tid = threadIdx.x;
    const int wi  = tid >> 6;   // 0..8
    const int t   = tid & 63;
    const int mwi = (wi < 8) ? wi : 7;  // wave 8: dummy DMA into unread slot 8
    // XCD-aware swizzle (kept since R2: FETCH 294->~72 MB)
    const int bid = blockIdx.x;
    const int bh  = (bid & 7) * 128 + (bid >> 3);
    const int b   = bh >> 8;
    const int h   = bh & 255;

    float acc[9][4];
#pragma unroll
    for (int jj = 0; jj < 9; ++jj)
#pragma unroll
        for (int s = 0; s < 4; ++s)
            acc[jj][s] = 0.f;

    const int r  = h + 4 - wi;                           // x2 row = h - i
    const int rr = (r < 0) ? 0 : ((r > 255) ? 255 : r);  // clamped, uniform path

    const float* x2p = x2 + (size_t)b * Cc * CH + (size_t)rr * Wc + 4 * t;
    const float* x1g = x1 + (size_t)b * Cc * CH + (size_t)h * Wc + 4 * t;

    float4 xq0, xq1, xq2, xq3;   // raw f32 x2 stage quads (lookahead 4 ch)
    float4 xc0, xc1, xn0, xn1;   // x1 current / next channel-pair quads

    // prologue: DMA group-0 x1 slab; prime x2 stages with channels 0..3.
    // queue [D_A, c0..c3] -> VMW(4) retires D_A; barrier; read x1 pair 0.
    GLOAD_LDS16(x1g + (size_t)mwi * CH, bufA + wi * 256);
    PIN();
    ISX(0, 0); ISX(1, 1); ISX(2, 2); ISX(3, 3);
    VMW(4);
    PIN(); __builtin_amdgcn_s_barrier(); PIN();
    RDX1(xc0, xc1, 0, 1, bufA);

#pragma unroll 1
    for (int g = 0; g < 3; ++g) {   // groups 0..5 (channels 0..47)
        GROUPN(bufA, bufB);
        GROUPN(bufB, bufA);
    }
    GROUPN(bufA, bufB);             // group 6 (48..55); stages 56..59 issued

    // tail: channels 56..63 from bufB; ladder 2,2,2,0
    RDX1(xn0, xn1, 2, 3, bufB); VMW(2); FMP(xq0, xq1, xc0, xc1);
    ISX(0, 4); ISX(1, 5);           // channels 60,61
    RDX1(xc0, xc1, 4, 5, bufB); VMW(2); FMP(xq2, xq3, xn0, xn1);
    ISX(2, 6); ISX(3, 7);           // channels 62,63
    RDX1(xn0, xn1, 6, 7, bufB); VMW(2); FMP(xq0, xq1, xc0, xc1);
    VMW(0); FMP(xq2, xq3, xn0, xn1);

    // invalid x2 rows (out of [0,256)) correlate to zero: wipe their acc
    if ((unsigned)r >= (unsigned)Hc) {
#pragma unroll
        for (int jj = 0; jj < 9; ++jj)
#pragma unroll
            for (int s = 0; s < 4; ++s)
                acc[jj][s] = 0.f;
    }

    __syncthreads();  // slabs dead; bufA becomes the reduction buffer
    float* red = bufA;

    // ---- softmax over 81 channels, reduced across the 9 waves ----
    float m0, m1, m2, m3;
    {
        float v0 = acc[0][0], v1 = acc[0][1], v2 = acc[0][2], v3 = acc[0][3];
#pragma unroll
        for (int jj = 1; jj < 9; ++jj) {
            v0 = fmaxf(v0, acc[jj][0]);
            v1 = fmaxf(v1, acc[jj][1]);
            v2 = fmaxf(v2, acc[jj][2]);
            v3 = fmaxf(v3, acc[jj][3]);
        }
        m0 = v0; m1 = v1; m2 = v2; m3 = v3;
    }
    *(float4*)(red + wi * 256 + 4 * t) = make_float4(m0, m1, m2, m3);
    __syncthreads();

    float M0, M1, M2, M3;
    {
        float4 q = *(const float4*)(red + 4 * t);
        M0 = q.x; M1 = q.y; M2 = q.z; M3 = q.w;
#pragma unroll
        for (int w2 = 1; w2 < 9; ++w2) {
            float4 qq = *(const float4*)(red + w2 * 256 + 4 * t);
            M0 = fmaxf(M0, qq.x); M1 = fmaxf(M1, qq.y);
            M2 = fmaxf(M2, qq.z); M3 = fmaxf(M3, qq.w);
        }
    }

    float s0 = 0.f, s1 = 0.f, s2 = 0.f, s3 = 0.f;
#pragma unroll
    for (int jj = 0; jj < 9; ++jj) {
        acc[jj][0] = __expf(acc[jj][0] - M0); s0 += acc[jj][0];
        acc[jj][1] = __expf(acc[jj][1] - M1); s1 += acc[jj][1];
        acc[jj][2] = __expf(acc[jj][2] - M2); s2 += acc[jj][2];
        acc[jj][3] = __expf(acc[jj][3] - M3); s3 += acc[jj][3];
    }
    __syncthreads();  // everyone done reading maxes
    *(float4*)(red + wi * 256 + 4 * t) = make_float4(s0, s1, s2, s3);
    __syncthreads();

    float S0, S1, S2, S3;
    {
        float4 q = *(const float4*)(red + 4 * t);
        S0 = q.x; S1 = q.y; S2 = q.z; S3 = q.w;
#pragma unroll
        for (int w2 = 1; w2 < 9; ++w2) {
            float4 qq = *(const float4*)(red + w2 * 256 + 4 * t);
            S0 += qq.x; S1 += qq.y; S2 += qq.z; S3 += qq.w;
        }
    }
    const float i0 = 1.0f / S0, i1 = 1.0f / S1, i2 = 1.0f / S2, i3 = 1.0f / S3;

    // k = (9*(wi-4) + (jj-4)) mod 81 = 9*wi + jj + 41 (mod 81)
    float* outp = out + (size_t)b * Dc * CH + (size_t)h * Wc + 4 * t;
#pragma unroll
    for (int jj = 0; jj < 9; ++jj) {
        int kc = 9 * wi + jj + 41;
        if (kc >= 81) kc -= 81;
        float4 o = make_float4(acc[jj][0] * i0, acc[jj][1] * i1,
                               acc[jj][2] * i2, acc[jj][3] * i3);
        *(float4*)(outp + (size_t)kc * CH) = o;
    }
}

extern "C" void kernel_launch(void* const* d_in, const int* in_sizes, int n_in,
                              void* d_out, int out_size, void* d_ws, size_t ws_size,
                              hipStream_t stream) {
    (void)in_sizes; (void)n_in; (void)d_ws; (void)ws_size; (void)out_size;
    const float* x1 = (const float*)d_in[0];
    const float* x2 = (const float*)d_in[1];
    float* out = (float*)d_out;
    dim3 grid(Bc * Hc);   // 1024 blocks: one per (b, h) row
    dim3 block(576);      // 9 waves
    hipLaunchKernelGGL(corr_softmax_kernel, grid, block, 0, stream, x1, x2, out);
}